// Round 1
// baseline (919.298 us; speedup 1.0000x reference)
//
#include <hip/hip_runtime.h>
#include <hip/hip_bf16.h>
#include <cstdint>

// Problem constants
// B=16, N=4096, S=1024 (NPOINT), K=32 (NSAMPLE), CIN=64, MLP 67->64->64->128
// M = B*S*K = 524288 rows through the MLP.

typedef __attribute__((ext_vector_type(8))) short bf16x8;
typedef __attribute__((ext_vector_type(4))) float f32x4;

#define LDA 104   // bf16 LDS row stride: 208 B = 52 dwords -> 2-way (free) b128 bank pattern

__device__ __forceinline__ unsigned short f2bf(float f) {
  unsigned x = __float_as_uint(f);
  unsigned r = (x + 0x7FFFu + ((x >> 16) & 1u)) >> 16;  // RNE
  return (unsigned short)r;
}
__device__ __forceinline__ float bf2f(unsigned short u) {
  return __uint_as_float(((unsigned)u) << 16);
}

// DPP max-combine on a packed 64-bit key. DPP row ops are VALU-latency (~2-4cyc)
// vs ~120cyc for ds_permute-backed __shfl — this is the FPS critical path.
template <int CTRL>
__device__ __forceinline__ unsigned long long dppmax(unsigned long long k) {
  int lo = (int)(unsigned)k;
  int hi = (int)(unsigned)(k >> 32);
  int plo = __builtin_amdgcn_update_dpp(lo, lo, CTRL, 0xF, 0xF, false);
  int phi = __builtin_amdgcn_update_dpp(hi, hi, CTRL, 0xF, 0xF, false);
  unsigned long long o =
      ((unsigned long long)(unsigned)phi << 32) | (unsigned)plo;
  return (o > k) ? o : k;
}

// Agent-scope acquire spin (consumers of FPS progress / prep completion).
__device__ __forceinline__ void spin_ge(int* p, int need) {
  while (__hip_atomic_load(p, __ATOMIC_ACQUIRE, __HIP_MEMORY_SCOPE_AGENT) < need)
    __builtin_amdgcn_s_sleep(32);
}

// ---------------------------------------------------------------------------
// MEGA kernel (cooperative, 256 blocks x 256 threads, 1 block/CU):
//   blocks 0..15  : FPS (verbatim r7 structure — measured structural floor
//                   614us; see notes below) + incremental publish of centers
//                   every 64 iters (wave-0 stores + threadfence + agent
//                   release of progress[b]; other waves don't stall).
//   blocks 16..255: (P1) stripe 1024 transpose tiles + 1 weight task, then
//                   release prep_done; (P3) pull GEMM1 tiles off a global
//                   ticket. Each tile does its OWN ball query (8 centers)
//                   into LDS — no ballidx global round-trip, no ball_kernel.
//   Ticket->tile mapping interleaves batches so ticket order == readiness
//   order (tile = (t%16)*128 + t/16). FPS blocks join the ticket loop at the
//   end to drain the tail.
//
// FPS STRUCTURAL FLOOR (r7-r9 measured): 8 waves = 666us (barrier-phase-locked
// waves only add skew). Packed-f32 + tree argmax = 879us. The chain is 1024
// serial iterations x ~1441cyc. Keep the FPS body — do not re-tweak without
// disasm. amdgpu_waves_per_eu(1,1) is required: the default VGPR heuristic
// caps at 64 regs and spills the 64-float point arrays (r3-r5).
//
// Memory-model chain: FPS release(progress) -> consumer acquire -> reads of
// centers4 are happens-before-ordered; prep_done is an RMW release sequence
// so one acquire of ==1025 synchronizes with all 240 releasers.
// Deadlock-freedom: producers (FPS, prep) depend on nothing; consumers only
// wait on producers; cooperative launch guarantees co-residency.
// ---------------------------------------------------------------------------
__global__ __attribute__((amdgpu_flat_work_group_size(256, 256),
                          amdgpu_waves_per_eu(1, 1)))
void mega_kernel(
    const float* __restrict__ xyz, const float* __restrict__ points,
    const float* __restrict__ W0, const float* __restrict__ W1,
    const float* __restrict__ W2, const float* __restrict__ b0,
    unsigned short* __restrict__ pT, unsigned short* __restrict__ w0t,
    unsigned short* __restrict__ w1t, unsigned short* __restrict__ w2t,
    float4* __restrict__ centers4, unsigned short* __restrict__ feats1,
    float* __restrict__ partials, float* __restrict__ out,
    int* __restrict__ ctrl)
{
  __shared__ __align__(16) char smraw[61568];
  __shared__ int tkt_s;
  int tid = threadIdx.x;
  int bx = blockIdx.x;
  int* progress  = ctrl;        // [16] centers published per batch
  int* prep_done = ctrl + 16;   // counts to 1025
  int* g1_ticket = ctrl + 17;   // gemm1 tile tickets

  if (bx < 16) {
    // ---- FPS path (body verbatim from the 614us floor version) ----
    float* xs  = (float*)smraw;                 // [4096]
    float* ys  = xs + 4096;                     // [4096]
    float* zs  = ys + 4096;                     // [4096]  (ends 49152 B)
    float* cxl = zs + 4096;                     // [1024]
    float* cyl = cxl + 1024;                    // [1024]
    float* czl = cyl + 1024;                    // [1024]  (ends 61440 B)
    unsigned long long (*keybuf)[4] =
        (unsigned long long (*)[4])(smraw + 61440);  // [2][4], 16B-aligned

    int b = bx;
    const float* xb = xyz + (size_t)b * 12288;
    float px[16], py[16], pz[16], dist[16];
#pragma unroll
    for (int j = 0; j < 16; ++j) {
      int n = tid + (j << 8);
      px[j] = xb[n]; py[j] = xb[4096 + n]; pz[j] = xb[8192 + n];
      xs[n] = px[j]; ys[n] = py[j]; zs[n] = pz[j];
      dist[j] = 1e10f;
    }
    __syncthreads();
    float cx = xs[0], cy = ys[0], cz = zs[0];
    if (tid == 0) { cxl[0] = cx; cyl[0] = cy; czl[0] = cz; }
    int w = tid >> 6;
    int lane = tid & 63;
    for (int it = 1; it < 1024; ++it) {
      float bv = -1.f; int bi = 0;
#pragma unroll
      for (int j = 0; j < 16; ++j) {
        float dx = __fsub_rn(px[j], cx);
        float dy = __fsub_rn(py[j], cy);
        float dz = __fsub_rn(pz[j], cz);
        float d  = __fadd_rn(__fadd_rn(__fmul_rn(dx, dx), __fmul_rn(dy, dy)),
                             __fmul_rn(dz, dz));
        float nd = fminf(dist[j], d);
        dist[j] = nd;
        if (nd > bv) { bv = nd; bi = tid + (j << 8); }  // strict >, j asc => min n
      }
      // pack: high 32 = dist bits (nonneg float => monotone), low 32 = ~n
      unsigned long long k =
          ((unsigned long long)__float_as_uint(bv) << 32) | (unsigned)(~bi);
      k = dppmax<0xB1>(k);    // quad_perm [1,0,3,2]  : xor 1
      k = dppmax<0x4E>(k);    // quad_perm [2,3,0,1]  : xor 2
      k = dppmax<0x141>(k);   // row_half_mirror      : xor 4
      k = dppmax<0x140>(k);   // row_mirror           : xor 8
      k = dppmax<0x142>(k);   // row_bcast15          : rows 0->1, 2->3
      k = dppmax<0x143>(k);   // row_bcast31          : rows 01 -> 23
      int p = it & 1;
      if (lane == 63) keybuf[p][w] = k;   // lane63 holds the wave max
      __syncthreads();
      // combine 4 wave keys: 2x b128 reads + 3-compare tree (uniform)
      uint4 ka2 = *(const uint4*)&keybuf[p][0];
      uint4 kb2 = *(const uint4*)&keybuf[p][2];
      unsigned long long k0 = ((unsigned long long)ka2.y << 32) | ka2.x;
      unsigned long long k1 = ((unsigned long long)ka2.w << 32) | ka2.z;
      unsigned long long k2 = ((unsigned long long)kb2.y << 32) | kb2.x;
      unsigned long long k3 = ((unsigned long long)kb2.w << 32) | kb2.z;
      unsigned long long m01 = (k1 > k0) ? k1 : k0;
      unsigned long long m23 = (k3 > k2) ? k3 : k2;
      unsigned long long km  = (m23 > m01) ? m23 : m01;
      int gi = (int)(~(unsigned)km) & 4095;
      cx = xs[gi]; cy = ys[gi]; cz = zs[gi];
      if (tid == 0) { cxl[it] = cx; cyl[it] = cy; czl[it] = cz; }
      // no second barrier: next iter writes keybuf[(it+1)&1], disjoint slot;
      // a wave re-writes this slot only after passing the NEXT barrier, which
      // orders it after every wave's read above.
      //
      // PUBLISH (new): every 64 iters wave 0 pushes the last 64 centers and
      // release-stores progress[b]. Only wave 0 pays the vmcnt+fence; it
      // catches up at the next mid-iteration barrier. cxl[base..it-1] are
      // wave-0-local LDS values (written by tid0) — no sync needed to read.
      if ((it & 63) == 0) {
        int base = it - 64;
        if (tid < 64) {
          int s = base + tid;
          centers4[(b << 10) + s] = make_float4(cxl[s], cyl[s], czl[s], 0.f);
        }
        if (tid == 0) {
          __threadfence();
          __hip_atomic_store(&progress[b], it, __ATOMIC_RELEASE,
                             __HIP_MEMORY_SCOPE_AGENT);
        }
      }
    }
    __syncthreads();
    for (int it = tid; it < 1024; it += 256) {
      float x = cxl[it], y = cyl[it], z = czl[it];
      out[b * 3072 + it]        = x;
      out[b * 3072 + 1024 + it] = y;
      out[b * 3072 + 2048 + it] = z;
      centers4[(b << 10) + it]  = make_float4(x, y, z, 0.f);
    }
    __syncthreads();   // drains every thread's center stores
    if (tid == 0) {
      __threadfence();
      __hip_atomic_store(&progress[b], 1024, __ATOMIC_RELEASE,
                         __HIP_MEMORY_SCOPE_AGENT);
    }
  } else {
    // ---- worker P1: prep tasks (1024 transposes + 1 weight fill) ----
    int wid = bx - 16;   // 0..239
    int cnt = 0;
    for (int t = wid; t < 1025; t += 240) {
      __syncthreads();   // tile reuse across tasks
      if (t < 1024) {
        float (*tile)[65] = (float (*)[65])smraw;
        int b = t >> 6;
        int n0 = (t & 63) << 6;
        const float* pbp = points + ((size_t)b << 18);
        for (int i = tid; i < 4096; i += 256) {
          int cc = i >> 6, nn = i & 63;
          tile[cc][nn] = pbp[((size_t)cc << 12) + n0 + nn];
        }
        __syncthreads();
        for (int i = tid; i < 4096; i += 256) {
          int nn = i >> 6, cc = i & 63;
          pT[(((size_t)((b << 12) + n0 + nn)) << 6) + cc] = f2bf(tile[cc][nn]);
        }
      } else {
        // w0t: 64x104, w1t: 64x104, w2t: 128x104 (stats zeroed by memset)
        for (int i = tid; i < 26624; i += 256) {
          if (i < 6656) {
            int nn = i / 104, kk = i % 104;
            float v = (kk < 64) ? W0[(3 + kk) * 64 + nn]
                                : ((kk < 67) ? W0[(kk - 64) * 64 + nn] : 0.f);
            w0t[i] = f2bf(v);
          } else if (i < 13312) {
            int j = i - 6656; int nn = j / 104, kk = j % 104;
            w1t[j] = f2bf((kk < 64) ? W1[kk * 64 + nn] : 0.f);
          } else {
            int j = i - 13312; int nn = j / 104, kk = j % 104;
            w2t[j] = f2bf((kk < 64) ? W2[kk * 128 + nn] : 0.f);
          }
        }
      }
      ++cnt;
    }
    __syncthreads();   // drains all threads' prep stores
    if (tid == 0) {
      __threadfence();
      __hip_atomic_fetch_add(prep_done, cnt, __ATOMIC_RELEASE,
                             __HIP_MEMORY_SCOPE_AGENT);
    }
  }

  // ---- common P3: GEMM1 tiles via global ticket (ball query fused) ----
  spin_ge(prep_done, 1025);
  __syncthreads();   // LDS role switch (FPS arrays / prep tile -> gemm layout)

  // LDS overlay: phase A (ball): xs/ys/zs 0..49152 + idxl tail.
  //              phase B (gemm): As 0..13312, Wt 13312..26624, red 26624..28672
  //              (all inside the then-dead xs/ys region), idxl tail survives.
  float* xs = (float*)smraw;
  float* ys = xs + 4096;
  float* zs = ys + 4096;
  unsigned short* As = (unsigned short*)smraw;            // 64*LDA
  unsigned short* Wt = (unsigned short*)(smraw + 13312);  // 64*LDA
  float* red = (float*)(smraw + 26624);                   // [2][4][64] flat
  int* idxl = (int*)(smraw + 60416);                      // [256]

  int lane = tid & 63, w = tid >> 6;
  int mrow = (w << 4) + (lane & 15);
  int quad = lane >> 4;
  unsigned long long lmask = (1ull << lane) - 1ull;

  for (;;) {
    if (tid == 0) tkt_s = atomicAdd(g1_ticket, 1);
    __syncthreads();
    int tk = tkt_s;
    if (tk >= 2048) break;
    // batch-interleaved mapping: ticket order == readiness order
    int tile = ((tk & 15) << 7) | (tk >> 4);
    int b = tile >> 7;
    int s0 = (tile & 127) << 3;          // first center (within batch)
    spin_ge(&progress[b], s0 + 8);

    // phase A: stage xyz, ball-query this tile's 8 centers into idxl.
    {
      const float* xb = xyz + (size_t)b * 12288;
      for (int i = tid; i < 4096; i += 256) {
        xs[i] = xb[i]; ys[i] = xb[4096 + i]; zs[i] = xb[8192 + i];
      }
    }
    __syncthreads();
    {
      int cg0 = (b << 10) + s0;
      for (int c2 = 0; c2 < 2; ++c2) {
        int sl = (w << 1) + c2;          // 2 centers per wave
        float4 c = centers4[cg0 + sl];
        int* ob = idxl + (sl << 5);
        int cnt2 = 0, first = 0;
        for (int m = 0; m < 64; ++m) {
          int n = (m << 6) + lane;
          float dx = __fsub_rn(xs[n], c.x);
          float dy = __fsub_rn(ys[n], c.y);
          float dz = __fsub_rn(zs[n], c.z);
          float d  = __fadd_rn(__fadd_rn(__fmul_rn(dx, dx), __fmul_rn(dy, dy)),
                               __fmul_rn(dz, dz));
          bool hit = !(d > 0.04f);       // 0.04f == f32(RADIUS**2)
          unsigned long long mask = __ballot(hit);
          if (cnt2 == 0 && mask != 0ull)
            first = (m << 6) + (__ffsll((long long)mask) - 1);
          int p = cnt2 + (int)__popcll(mask & lmask);
          if (hit && p < 32) ob[p] = n;
          cnt2 += (int)__popcll(mask);
          if (cnt2 >= 32) break;
        }
        if (lane < 32 && lane >= cnt2) ob[lane] = first;
      }
    }
    __syncthreads();

    // phase B: weight tile + 4 x 64-row sub-tiles (original gemm1 body)
    {
      const uint4* wsrc = (const uint4*)w0t;
      uint4* wdst = (uint4*)Wt;
      for (int i = tid; i < 832; i += 256) wdst[i] = wsrc[i];
    }
    float a0acc = 0.f, a1acc = 0.f;
    for (int tt = 0; tt < 4; ++tt) {
      int rowbase = (tile << 8) + (tt << 6);
      {
        int rl = tid >> 2, part = tid & 3;
        int n = idxl[(tt << 6) + rl];
        const uint4* psrc = (const uint4*)(pT + (((size_t)((b << 12) + n)) << 6));
        uint4* adst = (uint4*)(As + rl * LDA);
        adst[part * 2]     = psrc[part * 2];
        adst[part * 2 + 1] = psrc[part * 2 + 1];
        adst[8 + part] = make_uint4(0, 0, 0, 0);   // zero cols 64..95
        if (part == 0) {
          int r = rowbase + rl;
          float4 c = centers4[r >> 5];
          unsigned short* arow = As + rl * LDA;
          arow[64] = f2bf(__fsub_rn(xyz[(size_t)b * 12288 + n],        c.x));
          arow[65] = f2bf(__fsub_rn(xyz[(size_t)b * 12288 + 4096 + n], c.y));
          arow[66] = f2bf(__fsub_rn(xyz[(size_t)b * 12288 + 8192 + n], c.z));
        }
      }
      __syncthreads();
      f32x4 acc[4];
#pragma unroll
      for (int nt = 0; nt < 4; ++nt) acc[nt] = (f32x4){0.f, 0.f, 0.f, 0.f};
#pragma unroll
      for (int kt = 0; kt < 3; ++kt) {
        int ko = kt * 32 + (quad << 3);
        bf16x8 a = *(const bf16x8*)(As + mrow * LDA + ko);
#pragma unroll
        for (int nt = 0; nt < 4; ++nt) {
          bf16x8 bb = *(const bf16x8*)(Wt + ((nt << 4) + (lane & 15)) * LDA + ko);
          acc[nt] = __builtin_amdgcn_mfma_f32_16x16x32_bf16(a, bb, acc[nt], 0, 0, 0);
        }
      }
#pragma unroll
      for (int nt = 0; nt < 4; ++nt) {
        int cch = (nt << 4) + (lane & 15);
        float bias = b0[cch];
        float ssum = 0.f, sq = 0.f;
#pragma unroll
        for (int r2 = 0; r2 < 4; ++r2) {
          float y = acc[nt][r2] + bias;
          int ml = (w << 4) + (quad << 2) + r2;
          feats1[(((size_t)(rowbase + ml)) << 6) + cch] = f2bf(y);
          ssum += y; sq += y * y;
        }
        ssum += __shfl_xor(ssum, 16); ssum += __shfl_xor(ssum, 32);
        sq   += __shfl_xor(sq, 16);   sq   += __shfl_xor(sq, 32);
        if (quad == 0) { red[w * 64 + cch] = ssum; red[256 + w * 64 + cch] = sq; }
      }
      __syncthreads();
      if (tid < 64) {
        a0acc += red[tid] + red[64 + tid] + red[128 + tid] + red[192 + tid];
        a1acc += red[256 + tid] + red[320 + tid] + red[384 + tid] + red[448 + tid];
      }
      // next sub-tile's As staging is safe: every thread reaches it only
      // after the barrier above, which post-dates all As/Wt reads.
    }
    if (tid < 64) {
      partials[(size_t)tile * 256 + tid]      = a0acc;
      partials[(size_t)tile * 256 + 64 + tid] = a1acc;
    }
    __syncthreads();   // red reads + tkt_s done before next ticket's overwrite
  }
}

// ---------------------------------------------------------------------------
// GEMM2 (256 rows/block, 4 sub-tiles): A = relu(scale*y1+shift) from feats1;
// K=64; out raw y2 + partials.
// ---------------------------------------------------------------------------
__global__ __launch_bounds__(256) void gemm2_kernel(
    const unsigned short* __restrict__ featsIn, const unsigned short* __restrict__ wt,
    const float* __restrict__ bias_g, const float* __restrict__ ss_in,
    unsigned short* __restrict__ featsOut, float* __restrict__ partials)
{
  __shared__ unsigned short As[64 * LDA];
  __shared__ unsigned short Wt[64 * LDA];
  __shared__ float red[2][4][64];
  __shared__ float ssl[128];
  int tid = threadIdx.x;
  int blockbase = blockIdx.x << 8;
  if (tid < 128) ssl[tid] = ss_in[tid];
  {
    const uint4* wsrc = (const uint4*)wt;
    uint4* wdst = (uint4*)Wt;
    for (int i = tid; i < 832; i += 256) wdst[i] = wsrc[i];
  }
  int lane = tid & 63, w = tid >> 6;
  int mrow = (w << 4) + (lane & 15);
  int quad = lane >> 4;
  float a0acc = 0.f, a1acc = 0.f;
  __syncthreads();           // ssl/Wt visible before first use
  for (int t = 0; t < 4; ++t) {
    int rowbase = blockbase + (t << 6);
    {
      int rl = tid >> 2, part = tid & 3;
      size_t r = (size_t)rowbase + rl;
      union { uint4 v[2]; unsigned short u[16]; } tt;
      const uint4* src = (const uint4*)(featsIn + (r << 6));
      tt.v[0] = src[part * 2]; tt.v[1] = src[part * 2 + 1];
      union { uint4 v[2]; unsigned short u[16]; } o;
#pragma unroll
      for (int e = 0; e < 16; ++e) {
        int cch = (part << 4) + e;
        float f = bf2f(tt.u[e]);
        float y = fmaxf(f * ssl[cch] + ssl[64 + cch], 0.f);
        o.u[e] = f2bf(y);
      }
      uint4* adst = (uint4*)(As + rl * LDA + (part << 4));
      adst[0] = o.v[0]; adst[1] = o.v[1];
    }
    __syncthreads();
    f32x4 acc[4];
#pragma unroll
    for (int nt = 0; nt < 4; ++nt) acc[nt] = (f32x4){0.f, 0.f, 0.f, 0.f};
#pragma unroll
    for (int kt = 0; kt < 2; ++kt) {
      int ko = kt * 32 + (quad << 3);
      bf16x8 a = *(const bf16x8*)(As + mrow * LDA + ko);
#pragma unroll
      for (int nt = 0; nt < 4; ++nt) {
        bf16x8 bb = *(const bf16x8*)(Wt + ((nt << 4) + (lane & 15)) * LDA + ko);
        acc[nt] = __builtin_amdgcn_mfma_f32_16x16x32_bf16(a, bb, acc[nt], 0, 0, 0);
      }
    }
#pragma unroll
    for (int nt = 0; nt < 4; ++nt) {
      int cch = (nt << 4) + (lane & 15);
      float bias = bias_g[cch];
      float ssum = 0.f, sq = 0.f;
#pragma unroll
      for (int r2 = 0; r2 < 4; ++r2) {
        float y = acc[nt][r2] + bias;
        int ml = (w << 4) + (quad << 2) + r2;
        featsOut[(((size_t)(rowbase + ml)) << 6) + cch] = f2bf(y);
        ssum += y; sq += y * y;
      }
      ssum += __shfl_xor(ssum, 16); ssum += __shfl_xor(ssum, 32);
      sq   += __shfl_xor(sq, 16);   sq   += __shfl_xor(sq, 32);
      if (quad == 0) { red[0][w][cch] = ssum; red[1][w][cch] = sq; }
    }
    __syncthreads();
    if (tid < 64) {
      a0acc += red[0][0][tid] + red[0][1][tid] + red[0][2][tid] + red[0][3][tid];
      a1acc += red[1][0][tid] + red[1][1][tid] + red[1][2][tid] + red[1][3][tid];
    }
  }
  if (tid < 64) {
    partials[(size_t)blockIdx.x * 256 + tid]      = a0acc;
    partials[(size_t)blockIdx.x * 256 + 64 + tid] = a1acc;
  }
}

// ---------------------------------------------------------------------------
// GEMM3 stats + K-extremes (256 rows/block, 4 sub-tiles): y3 =
// relu2(feats2)@W2 + b2. Channel partials (sum,sumsq) accumulate across
// sub-tiles; per-(center,channel) max/min of raw y3 written per sub-tile.
// ---------------------------------------------------------------------------
__global__ __launch_bounds__(256) void gemm3_stats_kernel(
    const unsigned short* __restrict__ feats2, const unsigned short* __restrict__ w2t,
    const float* __restrict__ b2, const float* __restrict__ ss2,
    float* __restrict__ partials, float* __restrict__ y3mx,
    float* __restrict__ y3mn)
{
  __shared__ unsigned short As[64 * LDA];
  __shared__ unsigned short Wt[128 * LDA];
  __shared__ float red[2][4][128];
  __shared__ float mxw[4][128];
  __shared__ float mnw[4][128];
  __shared__ float ssl[128];
  int tid = threadIdx.x;
  int blockbase = blockIdx.x << 8;
  if (tid < 128) ssl[tid] = ss2[tid];
  {
    const uint4* wsrc = (const uint4*)w2t;
    uint4* wdst = (uint4*)Wt;
    for (int i = tid; i < 1664; i += 256) wdst[i] = wsrc[i];
  }
  int lane = tid & 63, w = tid >> 6;
  int mrow = (w << 4) + (lane & 15);
  int quad = lane >> 4;
  float a0acc = 0.f, a1acc = 0.f;
  __syncthreads();
  for (int t = 0; t < 4; ++t) {
    int rowbase = blockbase + (t << 6);
    {
      int rl = tid >> 2, part = tid & 3;
      size_t r = (size_t)rowbase + rl;
      union { uint4 v[2]; unsigned short u[16]; } tt;
      const uint4* src = (const uint4*)(feats2 + (r << 6));
      tt.v[0] = src[part * 2]; tt.v[1] = src[part * 2 + 1];
      union { uint4 v[2]; unsigned short u[16]; } o;
#pragma unroll
      for (int e = 0; e < 16; ++e) {
        int cch = (part << 4) + e;
        float f = bf2f(tt.u[e]);
        float y = fmaxf(f * ssl[cch] + ssl[64 + cch], 0.f);
        o.u[e] = f2bf(y);
      }
      uint4* adst = (uint4*)(As + rl * LDA + (part << 4));
      adst[0] = o.v[0]; adst[1] = o.v[1];
    }
    __syncthreads();
    f32x4 acc[8];
#pragma unroll
    for (int nt = 0; nt < 8; ++nt) acc[nt] = (f32x4){0.f, 0.f, 0.f, 0.f};
#pragma unroll
    for (int kt = 0; kt < 2; ++kt) {
      int ko = kt * 32 + (quad << 3);
      bf16x8 a = *(const bf16x8*)(As + mrow * LDA + ko);
#pragma unroll
      for (int nt = 0; nt < 8; ++nt) {
        bf16x8 bb = *(const bf16x8*)(Wt + ((nt << 4) + (lane & 15)) * LDA + ko);
        acc[nt] = __builtin_amdgcn_mfma_f32_16x16x32_bf16(a, bb, acc[nt], 0, 0, 0);
      }
    }
    // wave w's 16 rows belong to one center (center = w>>1 within sub-tile)
#pragma unroll
    for (int nt = 0; nt < 8; ++nt) {
      int cch = (nt << 4) + (lane & 15);
      float bias = b2[cch];
      float ssum = 0.f, sq = 0.f;
      float mx = -3.4e38f, mn = 3.4e38f;
#pragma unroll
      for (int r2 = 0; r2 < 4; ++r2) {
        float y = acc[nt][r2] + bias;
        ssum += y; sq += y * y;
        mx = fmaxf(mx, y); mn = fminf(mn, y);
      }
      ssum += __shfl_xor(ssum, 16); ssum += __shfl_xor(ssum, 32);
      sq   += __shfl_xor(sq, 16);   sq   += __shfl_xor(sq, 32);
      mx = fmaxf(mx, __shfl_xor(mx, 16)); mx = fmaxf(mx, __shfl_xor(mx, 32));
      mn = fminf(mn, __shfl_xor(mn, 16)); mn = fminf(mn, __shfl_xor(mn, 32));
      if (quad == 0) {
        red[0][w][cch] = ssum; red[1][w][cch] = sq;
        mxw[w][cch] = mx; mnw[w][cch] = mn;
      }
    }
    __syncthreads();
    if (tid < 128) {
      a0acc += red[0][0][tid] + red[0][1][tid] + red[0][2][tid] + red[0][3][tid];
      a1acc += red[1][0][tid] + red[1][1][tid] + red[1][2][tid] + red[1][3][tid];
    }
    {
      int c2 = tid >> 7, cch = tid & 127;
      int cg = (rowbase >> 5) + c2;          // global center index b*1024+s
      y3mx[((size_t)cg << 7) + cch] = fmaxf(mxw[2 * c2][cch], mxw[2 * c2 + 1][cch]);
      y3mn[((size_t)cg << 7) + cch] = fminf(mnw[2 * c2][cch], mnw[2 * c2 + 1][cch]);
    }
  }
  if (tid < 128) {
    partials[(size_t)blockIdx.x * 256 + tid]       = a0acc;
    partials[(size_t)blockIdx.x * 256 + 128 + tid] = a1acc;
  }
}

// ---------------------------------------------------------------------------
// stats reduce (partials 2048 rows: 64 blocks x 32 rows) + finalize
// ---------------------------------------------------------------------------
__global__ __launch_bounds__(256) void reduce_kernel(const float* __restrict__ partials,
                                                     float* __restrict__ stats, int twoC)
{
  int tid = threadIdx.x;
  if (tid < twoC) {
    int row0 = blockIdx.x << 5;
    float s = 0.f;
    for (int r = 0; r < 32; ++r) s += partials[((size_t)(row0 + r)) * 256 + tid];
    atomicAdd(&stats[tid], s);
  }
}

__global__ void finalize_kernel(const float* __restrict__ stats, const float* __restrict__ g,
                                const float* __restrict__ be, float* __restrict__ ss, int C)
{
  int c = threadIdx.x;
  if (c < C) {
    const float invM = 1.f / 524288.f;
    float mean = stats[c] * invM;
    float ex2  = stats[C + c] * invM;
    float var  = ex2 - mean * mean;
    float sc   = g[c] / sqrtf(var + 1e-5f);
    ss[c]     = sc;
    ss[C + c] = be[c] - mean * sc;
  }
}

// ---------------------------------------------------------------------------
// BN3 + K-max epilogue + transpose: read y3mx/y3mn [B*S,128], pick extreme by
// sign(sc), apply relu(sc*y+sh), write d_out [B,128,S] (offset 49152).
// ---------------------------------------------------------------------------
__global__ __launch_bounds__(256) void bn3_out_kernel(
    const float* __restrict__ y3mx, const float* __restrict__ y3mn,
    const float* __restrict__ ss3, float* __restrict__ out)
{
  __shared__ float t2[64][65];
  __shared__ float sl[128];
  int tid = threadIdx.x;
  int b = blockIdx.x >> 5;
  int rest = blockIdx.x & 31;
  int s0 = (rest & 15) << 6;
  int c0 = (rest >> 4) << 6;
  if (tid < 64) sl[tid] = ss3[c0 + tid];
  else if (tid < 128) sl[tid] = ss3[128 + c0 + (tid - 64)];
  __syncthreads();
  for (int i = tid; i < 4096; i += 256) {
    int row = i >> 6, col = i & 63;         // row = s within tile, col = ch
    size_t cg = (size_t)((b << 10) + s0 + row);
    float mx = y3mx[(cg << 7) + c0 + col];
    float mn = y3mn[(cg << 7) + c0 + col];
    float sc = sl[col], sh = sl[64 + col];
    float ye = (sc >= 0.f) ? mx : mn;
    t2[row][col] = fmaxf(ye * sc + sh, 0.f);
  }
  __syncthreads();
  for (int i = tid; i < 4096; i += 256) {
    int crow = i >> 6, scol = i & 63;
    out[49152 + ((size_t)b << 17) + (size_t)(c0 + crow) * 1024 + s0 + scol] = t2[scol][crow];
  }
}

// ---------------------------------------------------------------------------
extern "C" void kernel_launch(void* const* d_in, const int* in_sizes, int n_in,
                              void* d_out, int out_size, void* d_ws, size_t ws_size,
                              hipStream_t stream)
{
  (void)in_sizes; (void)n_in; (void)out_size; (void)ws_size;
  const float* xyz    = (const float*)d_in[0];
  const float* points = (const float*)d_in[1];
  const float* W0  = (const float*)d_in[2];
  const float* b0  = (const float*)d_in[3];
  const float* g0  = (const float*)d_in[4];
  const float* be0 = (const float*)d_in[5];
  const float* W1  = (const float*)d_in[6];
  const float* b1  = (const float*)d_in[7];
  const float* g1  = (const float*)d_in[8];
  const float* be1 = (const float*)d_in[9];
  const float* W2  = (const float*)d_in[10];
  const float* b2  = (const float*)d_in[11];
  const float* g2  = (const float*)d_in[12];
  const float* be2 = (const float*)d_in[13];
  float* out = (float*)d_out;

  char* base = (char*)d_ws;
  size_t off = 0;
  auto alloc = [&](size_t bytes) -> void* {
    void* p = base + off;
    off += (bytes + 255) & ~(size_t)255;
    return p;
  };
  unsigned short* pT     = (unsigned short*)alloc((size_t)16 * 4096 * 64 * 2);
  unsigned short* w0t    = (unsigned short*)alloc(64 * LDA * 2);
  unsigned short* w1t    = (unsigned short*)alloc(64 * LDA * 2);
  unsigned short* w2t    = (unsigned short*)alloc(128 * LDA * 2);
  float* stats_all       = (float*)alloc(512 * 4);
  float* ss_all          = (float*)alloc(512 * 4);
  float4* centers4       = (float4*)alloc((size_t)16 * 1024 * 16);
  unsigned short* feats1 = (unsigned short*)alloc((size_t)524288 * 64 * 2);
  unsigned short* feats2 = (unsigned short*)alloc((size_t)524288 * 64 * 2);
  float* partials        = (float*)alloc((size_t)2048 * 256 * 4);
  int* ctrl              = (int*)alloc(4096);

  // y3 extremes overlay the dead feats1 buffer (feats1 fully consumed by
  // gemm2 before gemm3_stats runs; 2 x 8.4MB fits in feats1's 67MB).
  float* y3mx = (float*)feats1;
  float* y3mn = y3mx + (size_t)16384 * 128;

  float* stats1 = stats_all;       float* stats2 = stats_all + 128; float* stats3 = stats_all + 256;
  float* ss1 = ss_all;             float* ss2 = ss_all + 128;       float* ss3 = ss_all + 256;

  // control block (progress/prep/ticket) and stats must be zero each launch
  hipMemsetAsync(ctrl, 0, 4096, stream);
  hipMemsetAsync(stats_all, 0, 512 * 4, stream);

  void* kargs[15] = {
    (void*)&xyz, (void*)&points, (void*)&W0, (void*)&W1, (void*)&W2,
    (void*)&b0, (void*)&pT, (void*)&w0t, (void*)&w1t, (void*)&w2t,
    (void*)&centers4, (void*)&feats1, (void*)&partials, (void*)&out,
    (void*)&ctrl
  };
  // cooperative launch guarantees all 256 blocks co-resident (1 block/CU),
  // making the producer->consumer spin-waits deadlock-free by construction.
  if (hipLaunchCooperativeKernel((void*)mega_kernel, dim3(256), dim3(256),
                                 kargs, 0, stream) != hipSuccess) {
    // fallback: 256 blocks == 256 CUs at 1 block/CU fills every CU on an
    // idle device; FPS blocks 0..15 dispatch first.
    mega_kernel<<<256, 256, 0, stream>>>(xyz, points, W0, W1, W2, b0, pT, w0t,
                                         w1t, w2t, centers4, feats1, partials,
                                         out, ctrl);
  }
  reduce_kernel<<<64, 256, 0, stream>>>(partials, stats1, 128);
  finalize_kernel<<<1, 64, 0, stream>>>(stats1, g0, be0, ss1, 64);
  gemm2_kernel<<<2048, 256, 0, stream>>>(feats1, w1t, b1, ss1, feats2, partials);
  reduce_kernel<<<64, 256, 0, stream>>>(partials, stats2, 128);
  finalize_kernel<<<1, 64, 0, stream>>>(stats2, g1, be1, ss2, 64);
  gemm3_stats_kernel<<<2048, 256, 0, stream>>>(feats2, w2t, b2, ss2, partials, y3mx, y3mn);
  reduce_kernel<<<64, 256, 0, stream>>>(partials, stats3, 256);
  finalize_kernel<<<1, 128, 0, stream>>>(stats3, g2, be2, ss3, 128);
  bn3_out_kernel<<<512, 256, 0, stream>>>(y3mx, y3mn, ss3, out);
}

// Round 2
// 893.948 us; speedup vs baseline: 1.0284x; 1.0284x over previous
//
#include <hip/hip_runtime.h>
#include <hip/hip_bf16.h>
#include <cstdint>

// Problem constants
// B=16, N=4096, S=1024 (NPOINT), K=32 (NSAMPLE), CIN=64, MLP 67->64->64->128
// M = B*S*K = 524288 rows through the MLP.

typedef __attribute__((ext_vector_type(8))) short bf16x8;
typedef __attribute__((ext_vector_type(4))) float f32x4;

#define LDA 104   // bf16 LDS row stride: 208 B = 52 dwords -> 2-way (free) b128 bank pattern

__device__ __forceinline__ unsigned short f2bf(float f) {
  unsigned x = __float_as_uint(f);
  unsigned r = (x + 0x7FFFu + ((x >> 16) & 1u)) >> 16;  // RNE
  return (unsigned short)r;
}
__device__ __forceinline__ float bf2f(unsigned short u) {
  return __uint_as_float(((unsigned)u) << 16);
}

// DPP max-combine on a packed 64-bit key. DPP row ops are VALU-latency (~2-4cyc)
// vs ~120cyc for ds_permute-backed __shfl — this is the FPS critical path.
template <int CTRL>
__device__ __forceinline__ unsigned long long dppmax(unsigned long long k) {
  int lo = (int)(unsigned)k;
  int hi = (int)(unsigned)(k >> 32);
  int plo = __builtin_amdgcn_update_dpp(lo, lo, CTRL, 0xF, 0xF, false);
  int phi = __builtin_amdgcn_update_dpp(hi, hi, CTRL, 0xF, 0xF, false);
  unsigned long long o =
      ((unsigned long long)(unsigned)phi << 32) | (unsigned)plo;
  return (o > k) ? o : k;
}

// Agent-scope acquire spin (consumers of FPS progress / prep completion).
__device__ __forceinline__ void spin_ge(int* p, int need) {
  while (__hip_atomic_load(p, __ATOMIC_ACQUIRE, __HIP_MEMORY_SCOPE_AGENT) < need)
    __builtin_amdgcn_s_sleep(32);
}

// ---------------------------------------------------------------------------
// MEGA kernel (cooperative, 256 blocks x 256 threads, 1 block/CU):
//   blocks 0..15  : FPS + segmented publish of centers every 64 iters.
//                   ROUND-2 FIX: round 1 put the publish (branch + global
//                   stores + threadfence) INSIDE the serial loop body and the
//                   FPS chain regressed 616->709us (~+215cy/iter — schedule
//                   perturbation of the dist-update pipeline). The loop is now
//                   peeled into 16 segments x 64 iterations with the inner
//                   body byte-identical to the measured 614us floor; publish
//                   runs between segments only.
//   blocks 16..255: (P1) stripe 1024 transpose tiles + 1 weight task, then
//                   release prep_done; (P3) pull GEMM1 tiles off a global
//                   ticket. Each tile does its OWN ball query (8 centers)
//                   into LDS — no ballidx global round-trip, no ball_kernel.
//   Ticket->tile mapping interleaves batches so ticket order == readiness
//   order (tile = (t%16)*128 + t/16). FPS blocks join the ticket loop at the
//   end to drain the tail.
//
// FPS STRUCTURAL FLOOR (r7-r9 measured): 8 waves = 666us (barrier-phase-locked
// waves only add skew). Packed-f32 + tree argmax = 879us. The chain is 1024
// serial iterations x ~1441cyc. Keep the FPS body — do not re-tweak without
// disasm. amdgpu_waves_per_eu(1,1) is required: the default VGPR heuristic
// caps at 64 regs and spills the 64-float point arrays (r3-r5).
//
// Memory-model chain: FPS release(progress) -> consumer acquire -> reads of
// centers4 are happens-before-ordered; prep_done is an RMW release sequence
// so one acquire of ==1025 synchronizes with all 240 releasers.
// Deadlock-freedom: producers (FPS, prep) depend on nothing; consumers only
// wait on producers; cooperative launch guarantees co-residency.
// ---------------------------------------------------------------------------
__global__ __attribute__((amdgpu_flat_work_group_size(256, 256),
                          amdgpu_waves_per_eu(1, 1)))
void mega_kernel(
    const float* __restrict__ xyz, const float* __restrict__ points,
    const float* __restrict__ W0, const float* __restrict__ W1,
    const float* __restrict__ W2, const float* __restrict__ b0,
    unsigned short* __restrict__ pT, unsigned short* __restrict__ w0t,
    unsigned short* __restrict__ w1t, unsigned short* __restrict__ w2t,
    float4* __restrict__ centers4, unsigned short* __restrict__ feats1,
    float* __restrict__ partials, float* __restrict__ out,
    int* __restrict__ ctrl)
{
  __shared__ __align__(16) char smraw[61568];
  __shared__ int tkt_s;
  int tid = threadIdx.x;
  int bx = blockIdx.x;
  int* progress  = ctrl;        // [16] centers published per batch
  int* prep_done = ctrl + 16;   // counts to 1025
  int* g1_ticket = ctrl + 17;   // gemm1 tile tickets

  if (bx < 16) {
    // ---- FPS path (inner body verbatim from the 614us floor version) ----
    float* xs  = (float*)smraw;                 // [4096]
    float* ys  = xs + 4096;                     // [4096]
    float* zs  = ys + 4096;                     // [4096]  (ends 49152 B)
    float* cxl = zs + 4096;                     // [1024]
    float* cyl = cxl + 1024;                    // [1024]
    float* czl = cyl + 1024;                    // [1024]  (ends 61440 B)
    unsigned long long (*keybuf)[4] =
        (unsigned long long (*)[4])(smraw + 61440);  // [2][4], 16B-aligned

    int b = bx;
    const float* xb = xyz + (size_t)b * 12288;
    float px[16], py[16], pz[16], dist[16];
#pragma unroll
    for (int j = 0; j < 16; ++j) {
      int n = tid + (j << 8);
      px[j] = xb[n]; py[j] = xb[4096 + n]; pz[j] = xb[8192 + n];
      xs[n] = px[j]; ys[n] = py[j]; zs[n] = pz[j];
      dist[j] = 1e10f;
    }
    __syncthreads();
    float cx = xs[0], cy = ys[0], cz = zs[0];
    if (tid == 0) { cxl[0] = cx; cyl[0] = cy; czl[0] = cz; }
    int w = tid >> 6;
    int lane = tid & 63;
    int it = 1;
#pragma unroll 1
    for (int seg = 0; seg < 16; ++seg) {
      int itend = (seg + 1) << 6;   // 64, 128, ..., 1024
#pragma unroll 1
      for (; it < itend; ++it) {
        float bv = -1.f; int bi = 0;
#pragma unroll
        for (int j = 0; j < 16; ++j) {
          float dx = __fsub_rn(px[j], cx);
          float dy = __fsub_rn(py[j], cy);
          float dz = __fsub_rn(pz[j], cz);
          float d  = __fadd_rn(__fadd_rn(__fmul_rn(dx, dx), __fmul_rn(dy, dy)),
                               __fmul_rn(dz, dz));
          float nd = fminf(dist[j], d);
          dist[j] = nd;
          if (nd > bv) { bv = nd; bi = tid + (j << 8); }  // strict >, j asc => min n
        }
        // pack: high 32 = dist bits (nonneg float => monotone), low 32 = ~n
        unsigned long long k =
            ((unsigned long long)__float_as_uint(bv) << 32) | (unsigned)(~bi);
        k = dppmax<0xB1>(k);    // quad_perm [1,0,3,2]  : xor 1
        k = dppmax<0x4E>(k);    // quad_perm [2,3,0,1]  : xor 2
        k = dppmax<0x141>(k);   // row_half_mirror      : xor 4
        k = dppmax<0x140>(k);   // row_mirror           : xor 8
        k = dppmax<0x142>(k);   // row_bcast15          : rows 0->1, 2->3
        k = dppmax<0x143>(k);   // row_bcast31          : rows 01 -> 23
        int p = it & 1;
        if (lane == 63) keybuf[p][w] = k;   // lane63 holds the wave max
        __syncthreads();
        // combine 4 wave keys: 2x b128 reads + 3-compare tree (uniform)
        uint4 ka2 = *(const uint4*)&keybuf[p][0];
        uint4 kb2 = *(const uint4*)&keybuf[p][2];
        unsigned long long k0 = ((unsigned long long)ka2.y << 32) | ka2.x;
        unsigned long long k1 = ((unsigned long long)ka2.w << 32) | ka2.z;
        unsigned long long k2 = ((unsigned long long)kb2.y << 32) | kb2.x;
        unsigned long long k3 = ((unsigned long long)kb2.w << 32) | kb2.z;
        unsigned long long m01 = (k1 > k0) ? k1 : k0;
        unsigned long long m23 = (k3 > k2) ? k3 : k2;
        unsigned long long km  = (m23 > m01) ? m23 : m01;
        int gi = (int)(~(unsigned)km) & 4095;
        cx = xs[gi]; cy = ys[gi]; cz = zs[gi];
        if (tid == 0) { cxl[it] = cx; cyl[it] = cy; czl[it] = cz; }
        // no second barrier: next iter writes keybuf[(it+1)&1], disjoint slot;
        // a wave re-writes this slot only after passing the NEXT barrier, which
        // orders it after every wave's read above.
      }
      // PUBLISH between segments (outside the hot loop's schedule): wave 0
      // pushes this segment's 64 centers and release-stores progress[b].
      // cxl[] entries are wave-0-local LDS values written by tid0 — the
      // compiler inserts the lgkmcnt wait for the intra-wave dependence.
      if (seg < 15) {
        if (tid < 64) {
          int s = (seg << 6) + tid;
          centers4[(b << 10) + s] = make_float4(cxl[s], cyl[s], czl[s], 0.f);
        }
        if (tid == 0) {
          __threadfence();
          __hip_atomic_store(&progress[b], itend, __ATOMIC_RELEASE,
                             __HIP_MEMORY_SCOPE_AGENT);
        }
      }
    }
    __syncthreads();
    for (int s = tid; s < 1024; s += 256) {
      float x = cxl[s], y = cyl[s], z = czl[s];
      out[b * 3072 + s]        = x;
      out[b * 3072 + 1024 + s] = y;
      out[b * 3072 + 2048 + s] = z;
      centers4[(b << 10) + s]  = make_float4(x, y, z, 0.f);
    }
    __syncthreads();   // drains every thread's center stores
    if (tid == 0) {
      __threadfence();
      __hip_atomic_store(&progress[b], 1024, __ATOMIC_RELEASE,
                         __HIP_MEMORY_SCOPE_AGENT);
    }
  } else {
    // ---- worker P1: prep tasks (1024 transposes + 1 weight fill) ----
    int wid = bx - 16;   // 0..239
    int cnt = 0;
    for (int t = wid; t < 1025; t += 240) {
      __syncthreads();   // tile reuse across tasks
      if (t < 1024) {
        float (*tile)[65] = (float (*)[65])smraw;
        int b = t >> 6;
        int n0 = (t & 63) << 6;
        const float* pbp = points + ((size_t)b << 18);
        for (int i = tid; i < 4096; i += 256) {
          int cc = i >> 6, nn = i & 63;
          tile[cc][nn] = pbp[((size_t)cc << 12) + n0 + nn];
        }
        __syncthreads();
        for (int i = tid; i < 4096; i += 256) {
          int nn = i >> 6, cc = i & 63;
          pT[(((size_t)((b << 12) + n0 + nn)) << 6) + cc] = f2bf(tile[cc][nn]);
        }
      } else {
        // w0t: 64x104, w1t: 64x104, w2t: 128x104 (stats zeroed by memset)
        for (int i = tid; i < 26624; i += 256) {
          if (i < 6656) {
            int nn = i / 104, kk = i % 104;
            float v = (kk < 64) ? W0[(3 + kk) * 64 + nn]
                                : ((kk < 67) ? W0[(kk - 64) * 64 + nn] : 0.f);
            w0t[i] = f2bf(v);
          } else if (i < 13312) {
            int j = i - 6656; int nn = j / 104, kk = j % 104;
            w1t[j] = f2bf((kk < 64) ? W1[kk * 64 + nn] : 0.f);
          } else {
            int j = i - 13312; int nn = j / 104, kk = j % 104;
            w2t[j] = f2bf((kk < 64) ? W2[kk * 128 + nn] : 0.f);
          }
        }
      }
      ++cnt;
    }
    __syncthreads();   // drains all threads' prep stores
    if (tid == 0) {
      __threadfence();
      __hip_atomic_fetch_add(prep_done, cnt, __ATOMIC_RELEASE,
                             __HIP_MEMORY_SCOPE_AGENT);
    }
  }

  // ---- common P3: GEMM1 tiles via global ticket (ball query fused) ----
  spin_ge(prep_done, 1025);
  __syncthreads();   // LDS role switch (FPS arrays / prep tile -> gemm layout)

  // LDS overlay: phase A (ball): xs/ys/zs 0..49152 + idxl tail.
  //              phase B (gemm): As 0..13312, Wt 13312..26624, red 26624..28672
  //              (all inside the then-dead xs/ys region), idxl tail survives.
  float* xs = (float*)smraw;
  float* ys = xs + 4096;
  float* zs = ys + 4096;
  unsigned short* As = (unsigned short*)smraw;            // 64*LDA
  unsigned short* Wt = (unsigned short*)(smraw + 13312);  // 64*LDA
  float* red = (float*)(smraw + 26624);                   // [2][4][64] flat
  int* idxl = (int*)(smraw + 60416);                      // [256]

  int lane = tid & 63, w = tid >> 6;
  int mrow = (w << 4) + (lane & 15);
  int quad = lane >> 4;
  unsigned long long lmask = (1ull << lane) - 1ull;

  for (;;) {
    if (tid == 0) tkt_s = atomicAdd(g1_ticket, 1);
    __syncthreads();
    int tk = tkt_s;
    if (tk >= 2048) break;
    // batch-interleaved mapping: ticket order == readiness order
    int tile = ((tk & 15) << 7) | (tk >> 4);
    int b = tile >> 7;
    int s0 = (tile & 127) << 3;          // first center (within batch)
    spin_ge(&progress[b], s0 + 8);

    // phase A: stage xyz, ball-query this tile's 8 centers into idxl.
    {
      const float* xb = xyz + (size_t)b * 12288;
      for (int i = tid; i < 4096; i += 256) {
        xs[i] = xb[i]; ys[i] = xb[4096 + i]; zs[i] = xb[8192 + i];
      }
    }
    __syncthreads();
    {
      int cg0 = (b << 10) + s0;
      for (int c2 = 0; c2 < 2; ++c2) {
        int sl = (w << 1) + c2;          // 2 centers per wave
        float4 c = centers4[cg0 + sl];
        int* ob = idxl + (sl << 5);
        int cnt2 = 0, first = 0;
        for (int m = 0; m < 64; ++m) {
          int n = (m << 6) + lane;
          float dx = __fsub_rn(xs[n], c.x);
          float dy = __fsub_rn(ys[n], c.y);
          float dz = __fsub_rn(zs[n], c.z);
          float d  = __fadd_rn(__fadd_rn(__fmul_rn(dx, dx), __fmul_rn(dy, dy)),
                               __fmul_rn(dz, dz));
          bool hit = !(d > 0.04f);       // 0.04f == f32(RADIUS**2)
          unsigned long long mask = __ballot(hit);
          if (cnt2 == 0 && mask != 0ull)
            first = (m << 6) + (__ffsll((long long)mask) - 1);
          int p = cnt2 + (int)__popcll(mask & lmask);
          if (hit && p < 32) ob[p] = n;
          cnt2 += (int)__popcll(mask);
          if (cnt2 >= 32) break;
        }
        if (lane < 32 && lane >= cnt2) ob[lane] = first;
      }
    }
    __syncthreads();

    // phase B: weight tile + 4 x 64-row sub-tiles (original gemm1 body)
    {
      const uint4* wsrc = (const uint4*)w0t;
      uint4* wdst = (uint4*)Wt;
      for (int i = tid; i < 832; i += 256) wdst[i] = wsrc[i];
    }
    float a0acc = 0.f, a1acc = 0.f;
    for (int tt = 0; tt < 4; ++tt) {
      int rowbase = (tile << 8) + (tt << 6);
      {
        int rl = tid >> 2, part = tid & 3;
        int n = idxl[(tt << 6) + rl];
        const uint4* psrc = (const uint4*)(pT + (((size_t)((b << 12) + n)) << 6));
        uint4* adst = (uint4*)(As + rl * LDA);
        adst[part * 2]     = psrc[part * 2];
        adst[part * 2 + 1] = psrc[part * 2 + 1];
        adst[8 + part] = make_uint4(0, 0, 0, 0);   // zero cols 64..95
        if (part == 0) {
          int r = rowbase + rl;
          float4 c = centers4[r >> 5];
          unsigned short* arow = As + rl * LDA;
          arow[64] = f2bf(__fsub_rn(xyz[(size_t)b * 12288 + n],        c.x));
          arow[65] = f2bf(__fsub_rn(xyz[(size_t)b * 12288 + 4096 + n], c.y));
          arow[66] = f2bf(__fsub_rn(xyz[(size_t)b * 12288 + 8192 + n], c.z));
        }
      }
      __syncthreads();
      f32x4 acc[4];
#pragma unroll
      for (int nt = 0; nt < 4; ++nt) acc[nt] = (f32x4){0.f, 0.f, 0.f, 0.f};
#pragma unroll
      for (int kt = 0; kt < 3; ++kt) {
        int ko = kt * 32 + (quad << 3);
        bf16x8 a = *(const bf16x8*)(As + mrow * LDA + ko);
#pragma unroll
        for (int nt = 0; nt < 4; ++nt) {
          bf16x8 bb = *(const bf16x8*)(Wt + ((nt << 4) + (lane & 15)) * LDA + ko);
          acc[nt] = __builtin_amdgcn_mfma_f32_16x16x32_bf16(a, bb, acc[nt], 0, 0, 0);
        }
      }
#pragma unroll
      for (int nt = 0; nt < 4; ++nt) {
        int cch = (nt << 4) + (lane & 15);
        float bias = b0[cch];
        float ssum = 0.f, sq = 0.f;
#pragma unroll
        for (int r2 = 0; r2 < 4; ++r2) {
          float y = acc[nt][r2] + bias;
          int ml = (w << 4) + (quad << 2) + r2;
          feats1[(((size_t)(rowbase + ml)) << 6) + cch] = f2bf(y);
          ssum += y; sq += y * y;
        }
        ssum += __shfl_xor(ssum, 16); ssum += __shfl_xor(ssum, 32);
        sq   += __shfl_xor(sq, 16);   sq   += __shfl_xor(sq, 32);
        if (quad == 0) { red[w * 64 + cch] = ssum; red[256 + w * 64 + cch] = sq; }
      }
      __syncthreads();
      if (tid < 64) {
        a0acc += red[tid] + red[64 + tid] + red[128 + tid] + red[192 + tid];
        a1acc += red[256 + tid] + red[320 + tid] + red[384 + tid] + red[448 + tid];
      }
      // next sub-tile's As staging is safe: every thread reaches it only
      // after the barrier above, which post-dates all As/Wt reads.
    }
    if (tid < 64) {
      partials[(size_t)tile * 256 + tid]      = a0acc;
      partials[(size_t)tile * 256 + 64 + tid] = a1acc;
    }
    __syncthreads();   // red reads + tkt_s done before next ticket's overwrite
  }
}

// ---------------------------------------------------------------------------
// GEMM2 (256 rows/block, 4 sub-tiles): A = relu(scale*y1+shift) from feats1;
// K=64; out raw y2 + partials.
// ---------------------------------------------------------------------------
__global__ __launch_bounds__(256) void gemm2_kernel(
    const unsigned short* __restrict__ featsIn, const unsigned short* __restrict__ wt,
    const float* __restrict__ bias_g, const float* __restrict__ ss_in,
    unsigned short* __restrict__ featsOut, float* __restrict__ partials)
{
  __shared__ unsigned short As[64 * LDA];
  __shared__ unsigned short Wt[64 * LDA];
  __shared__ float red[2][4][64];
  __shared__ float ssl[128];
  int tid = threadIdx.x;
  int blockbase = blockIdx.x << 8;
  if (tid < 128) ssl[tid] = ss_in[tid];
  {
    const uint4* wsrc = (const uint4*)wt;
    uint4* wdst = (uint4*)Wt;
    for (int i = tid; i < 832; i += 256) wdst[i] = wsrc[i];
  }
  int lane = tid & 63, w = tid >> 6;
  int mrow = (w << 4) + (lane & 15);
  int quad = lane >> 4;
  float a0acc = 0.f, a1acc = 0.f;
  __syncthreads();           // ssl/Wt visible before first use
  for (int t = 0; t < 4; ++t) {
    int rowbase = blockbase + (t << 6);
    {
      int rl = tid >> 2, part = tid & 3;
      size_t r = (size_t)rowbase + rl;
      union { uint4 v[2]; unsigned short u[16]; } tt;
      const uint4* src = (const uint4*)(featsIn + (r << 6));
      tt.v[0] = src[part * 2]; tt.v[1] = src[part * 2 + 1];
      union { uint4 v[2]; unsigned short u[16]; } o;
#pragma unroll
      for (int e = 0; e < 16; ++e) {
        int cch = (part << 4) + e;
        float f = bf2f(tt.u[e]);
        float y = fmaxf(f * ssl[cch] + ssl[64 + cch], 0.f);
        o.u[e] = f2bf(y);
      }
      uint4* adst = (uint4*)(As + rl * LDA + (part << 4));
      adst[0] = o.v[0]; adst[1] = o.v[1];
    }
    __syncthreads();
    f32x4 acc[4];
#pragma unroll
    for (int nt = 0; nt < 4; ++nt) acc[nt] = (f32x4){0.f, 0.f, 0.f, 0.f};
#pragma unroll
    for (int kt = 0; kt < 2; ++kt) {
      int ko = kt * 32 + (quad << 3);
      bf16x8 a = *(const bf16x8*)(As + mrow * LDA + ko);
#pragma unroll
      for (int nt = 0; nt < 4; ++nt) {
        bf16x8 bb = *(const bf16x8*)(Wt + ((nt << 4) + (lane & 15)) * LDA + ko);
        acc[nt] = __builtin_amdgcn_mfma_f32_16x16x32_bf16(a, bb, acc[nt], 0, 0, 0);
      }
    }
#pragma unroll
    for (int nt = 0; nt < 4; ++nt) {
      int cch = (nt << 4) + (lane & 15);
      float bias = bias_g[cch];
      float ssum = 0.f, sq = 0.f;
#pragma unroll
      for (int r2 = 0; r2 < 4; ++r2) {
        float y = acc[nt][r2] + bias;
        int ml = (w << 4) + (quad << 2) + r2;
        featsOut[(((size_t)(rowbase + ml)) << 6) + cch] = f2bf(y);
        ssum += y; sq += y * y;
      }
      ssum += __shfl_xor(ssum, 16); ssum += __shfl_xor(ssum, 32);
      sq   += __shfl_xor(sq, 16);   sq   += __shfl_xor(sq, 32);
      if (quad == 0) { red[0][w][cch] = ssum; red[1][w][cch] = sq; }
    }
    __syncthreads();
    if (tid < 64) {
      a0acc += red[0][0][tid] + red[0][1][tid] + red[0][2][tid] + red[0][3][tid];
      a1acc += red[1][0][tid] + red[1][1][tid] + red[1][2][tid] + red[1][3][tid];
    }
  }
  if (tid < 64) {
    partials[(size_t)blockIdx.x * 256 + tid]      = a0acc;
    partials[(size_t)blockIdx.x * 256 + 64 + tid] = a1acc;
  }
}

// ---------------------------------------------------------------------------
// GEMM3 stats + K-extremes (256 rows/block, 4 sub-tiles): y3 =
// relu2(feats2)@W2 + b2. Channel partials (sum,sumsq) accumulate across
// sub-tiles; per-(center,channel) max/min of raw y3 written per sub-tile.
// ---------------------------------------------------------------------------
__global__ __launch_bounds__(256) void gemm3_stats_kernel(
    const unsigned short* __restrict__ feats2, const unsigned short* __restrict__ w2t,
    const float* __restrict__ b2, const float* __restrict__ ss2,
    float* __restrict__ partials, float* __restrict__ y3mx,
    float* __restrict__ y3mn)
{
  __shared__ unsigned short As[64 * LDA];
  __shared__ unsigned short Wt[128 * LDA];
  __shared__ float red[2][4][128];
  __shared__ float mxw[4][128];
  __shared__ float mnw[4][128];
  __shared__ float ssl[128];
  int tid = threadIdx.x;
  int blockbase = blockIdx.x << 8;
  if (tid < 128) ssl[tid] = ss2[tid];
  {
    const uint4* wsrc = (const uint4*)w2t;
    uint4* wdst = (uint4*)Wt;
    for (int i = tid; i < 1664; i += 256) wdst[i] = wsrc[i];
  }
  int lane = tid & 63, w = tid >> 6;
  int mrow = (w << 4) + (lane & 15);
  int quad = lane >> 4;
  float a0acc = 0.f, a1acc = 0.f;
  __syncthreads();
  for (int t = 0; t < 4; ++t) {
    int rowbase = blockbase + (t << 6);
    {
      int rl = tid >> 2, part = tid & 3;
      size_t r = (size_t)rowbase + rl;
      union { uint4 v[2]; unsigned short u[16]; } tt;
      const uint4* src = (const uint4*)(feats2 + (r << 6));
      tt.v[0] = src[part * 2]; tt.v[1] = src[part * 2 + 1];
      union { uint4 v[2]; unsigned short u[16]; } o;
#pragma unroll
      for (int e = 0; e < 16; ++e) {
        int cch = (part << 4) + e;
        float f = bf2f(tt.u[e]);
        float y = fmaxf(f * ssl[cch] + ssl[64 + cch], 0.f);
        o.u[e] = f2bf(y);
      }
      uint4* adst = (uint4*)(As + rl * LDA + (part << 4));
      adst[0] = o.v[0]; adst[1] = o.v[1];
    }
    __syncthreads();
    f32x4 acc[8];
#pragma unroll
    for (int nt = 0; nt < 8; ++nt) acc[nt] = (f32x4){0.f, 0.f, 0.f, 0.f};
#pragma unroll
    for (int kt = 0; kt < 2; ++kt) {
      int ko = kt * 32 + (quad << 3);
      bf16x8 a = *(const bf16x8*)(As + mrow * LDA + ko);
#pragma unroll
      for (int nt = 0; nt < 8; ++nt) {
        bf16x8 bb = *(const bf16x8*)(Wt + ((nt << 4) + (lane & 15)) * LDA + ko);
        acc[nt] = __builtin_amdgcn_mfma_f32_16x16x32_bf16(a, bb, acc[nt], 0, 0, 0);
      }
    }
    // wave w's 16 rows belong to one center (center = w>>1 within sub-tile)
#pragma unroll
    for (int nt = 0; nt < 8; ++nt) {
      int cch = (nt << 4) + (lane & 15);
      float bias = b2[cch];
      float ssum = 0.f, sq = 0.f;
      float mx = -3.4e38f, mn = 3.4e38f;
#pragma unroll
      for (int r2 = 0; r2 < 4; ++r2) {
        float y = acc[nt][r2] + bias;
        ssum += y; sq += y * y;
        mx = fmaxf(mx, y); mn = fminf(mn, y);
      }
      ssum += __shfl_xor(ssum, 16); ssum += __shfl_xor(ssum, 32);
      sq   += __shfl_xor(sq, 16);   sq   += __shfl_xor(sq, 32);
      mx = fmaxf(mx, __shfl_xor(mx, 16)); mx = fmaxf(mx, __shfl_xor(mx, 32));
      mn = fminf(mn, __shfl_xor(mn, 16)); mn = fminf(mn, __shfl_xor(mn, 32));
      if (quad == 0) {
        red[0][w][cch] = ssum; red[1][w][cch] = sq;
        mxw[w][cch] = mx; mnw[w][cch] = mn;
      }
    }
    __syncthreads();
    if (tid < 128) {
      a0acc += red[0][0][tid] + red[0][1][tid] + red[0][2][tid] + red[0][3][tid];
      a1acc += red[1][0][tid] + red[1][1][tid] + red[1][2][tid] + red[1][3][tid];
    }
    {
      int c2 = tid >> 7, cch = tid & 127;
      int cg = (rowbase >> 5) + c2;          // global center index b*1024+s
      y3mx[((size_t)cg << 7) + cch] = fmaxf(mxw[2 * c2][cch], mxw[2 * c2 + 1][cch]);
      y3mn[((size_t)cg << 7) + cch] = fminf(mnw[2 * c2][cch], mnw[2 * c2 + 1][cch]);
    }
  }
  if (tid < 128) {
    partials[(size_t)blockIdx.x * 256 + tid]       = a0acc;
    partials[(size_t)blockIdx.x * 256 + 128 + tid] = a1acc;
  }
}

// ---------------------------------------------------------------------------
// stats reduce (partials 2048 rows: 64 blocks x 32 rows) + finalize
// ---------------------------------------------------------------------------
__global__ __launch_bounds__(256) void reduce_kernel(const float* __restrict__ partials,
                                                     float* __restrict__ stats, int twoC)
{
  int tid = threadIdx.x;
  if (tid < twoC) {
    int row0 = blockIdx.x << 5;
    float s = 0.f;
    for (int r = 0; r < 32; ++r) s += partials[((size_t)(row0 + r)) * 256 + tid];
    atomicAdd(&stats[tid], s);
  }
}

__global__ void finalize_kernel(const float* __restrict__ stats, const float* __restrict__ g,
                                const float* __restrict__ be, float* __restrict__ ss, int C)
{
  int c = threadIdx.x;
  if (c < C) {
    const float invM = 1.f / 524288.f;
    float mean = stats[c] * invM;
    float ex2  = stats[C + c] * invM;
    float var  = ex2 - mean * mean;
    float sc   = g[c] / sqrtf(var + 1e-5f);
    ss[c]     = sc;
    ss[C + c] = be[c] - mean * sc;
  }
}

// ---------------------------------------------------------------------------
// BN3 + K-max epilogue + transpose: read y3mx/y3mn [B*S,128], pick extreme by
// sign(sc), apply relu(sc*y+sh), write d_out [B,128,S] (offset 49152).
// ---------------------------------------------------------------------------
__global__ __launch_bounds__(256) void bn3_out_kernel(
    const float* __restrict__ y3mx, const float* __restrict__ y3mn,
    const float* __restrict__ ss3, float* __restrict__ out)
{
  __shared__ float t2[64][65];
  __shared__ float sl[128];
  int tid = threadIdx.x;
  int b = blockIdx.x >> 5;
  int rest = blockIdx.x & 31;
  int s0 = (rest & 15) << 6;
  int c0 = (rest >> 4) << 6;
  if (tid < 64) sl[tid] = ss3[c0 + tid];
  else if (tid < 128) sl[tid] = ss3[128 + c0 + (tid - 64)];
  __syncthreads();
  for (int i = tid; i < 4096; i += 256) {
    int row = i >> 6, col = i & 63;         // row = s within tile, col = ch
    size_t cg = (size_t)((b << 10) + s0 + row);
    float mx = y3mx[(cg << 7) + c0 + col];
    float mn = y3mn[(cg << 7) + c0 + col];
    float sc = sl[col], sh = sl[64 + col];
    float ye = (sc >= 0.f) ? mx : mn;
    t2[row][col] = fmaxf(ye * sc + sh, 0.f);
  }
  __syncthreads();
  for (int i = tid; i < 4096; i += 256) {
    int crow = i >> 6, scol = i & 63;
    out[49152 + ((size_t)b << 17) + (size_t)(c0 + crow) * 1024 + s0 + scol] = t2[scol][crow];
  }
}

// ---------------------------------------------------------------------------
extern "C" void kernel_launch(void* const* d_in, const int* in_sizes, int n_in,
                              void* d_out, int out_size, void* d_ws, size_t ws_size,
                              hipStream_t stream)
{
  (void)in_sizes; (void)n_in; (void)out_size; (void)ws_size;
  const float* xyz    = (const float*)d_in[0];
  const float* points = (const float*)d_in[1];
  const float* W0  = (const float*)d_in[2];
  const float* b0  = (const float*)d_in[3];
  const float* g0  = (const float*)d_in[4];
  const float* be0 = (const float*)d_in[5];
  const float* W1  = (const float*)d_in[6];
  const float* b1  = (const float*)d_in[7];
  const float* g1  = (const float*)d_in[8];
  const float* be1 = (const float*)d_in[9];
  const float* W2  = (const float*)d_in[10];
  const float* b2  = (const float*)d_in[11];
  const float* g2  = (const float*)d_in[12];
  const float* be2 = (const float*)d_in[13];
  float* out = (float*)d_out;

  char* base = (char*)d_ws;
  size_t off = 0;
  auto alloc = [&](size_t bytes) -> void* {
    void* p = base + off;
    off += (bytes + 255) & ~(size_t)255;
    return p;
  };
  unsigned short* pT     = (unsigned short*)alloc((size_t)16 * 4096 * 64 * 2);
  unsigned short* w0t    = (unsigned short*)alloc(64 * LDA * 2);
  unsigned short* w1t    = (unsigned short*)alloc(64 * LDA * 2);
  unsigned short* w2t    = (unsigned short*)alloc(128 * LDA * 2);
  float* stats_all       = (float*)alloc(512 * 4);
  float* ss_all          = (float*)alloc(512 * 4);
  float4* centers4       = (float4*)alloc((size_t)16 * 1024 * 16);
  unsigned short* feats1 = (unsigned short*)alloc((size_t)524288 * 64 * 2);
  unsigned short* feats2 = (unsigned short*)alloc((size_t)524288 * 64 * 2);
  float* partials        = (float*)alloc((size_t)2048 * 256 * 4);
  int* ctrl              = (int*)alloc(4096);

  // y3 extremes overlay the dead feats1 buffer (feats1 fully consumed by
  // gemm2 before gemm3_stats runs; 2 x 8.4MB fits in feats1's 67MB).
  float* y3mx = (float*)feats1;
  float* y3mn = y3mx + (size_t)16384 * 128;

  float* stats1 = stats_all;       float* stats2 = stats_all + 128; float* stats3 = stats_all + 256;
  float* ss1 = ss_all;             float* ss2 = ss_all + 128;       float* ss3 = ss_all + 256;

  // control block (progress/prep/ticket) and stats must be zero each launch
  hipMemsetAsync(ctrl, 0, 4096, stream);
  hipMemsetAsync(stats_all, 0, 512 * 4, stream);

  void* kargs[15] = {
    (void*)&xyz, (void*)&points, (void*)&W0, (void*)&W1, (void*)&W2,
    (void*)&b0, (void*)&pT, (void*)&w0t, (void*)&w1t, (void*)&w2t,
    (void*)&centers4, (void*)&feats1, (void*)&partials, (void*)&out,
    (void*)&ctrl
  };
  // cooperative launch guarantees all 256 blocks co-resident (1 block/CU),
  // making the producer->consumer spin-waits deadlock-free by construction.
  if (hipLaunchCooperativeKernel((void*)mega_kernel, dim3(256), dim3(256),
                                 kargs, 0, stream) != hipSuccess) {
    // fallback: 256 blocks == 256 CUs at 1 block/CU fills every CU on an
    // idle device; FPS blocks 0..15 dispatch first.
    mega_kernel<<<256, 256, 0, stream>>>(xyz, points, W0, W1, W2, b0, pT, w0t,
                                         w1t, w2t, centers4, feats1, partials,
                                         out, ctrl);
  }
  reduce_kernel<<<64, 256, 0, stream>>>(partials, stats1, 128);
  finalize_kernel<<<1, 64, 0, stream>>>(stats1, g0, be0, ss1, 64);
  gemm2_kernel<<<2048, 256, 0, stream>>>(feats1, w1t, b1, ss1, feats2, partials);
  reduce_kernel<<<64, 256, 0, stream>>>(partials, stats2, 128);
  finalize_kernel<<<1, 64, 0, stream>>>(stats2, g1, be1, ss2, 64);
  gemm3_stats_kernel<<<2048, 256, 0, stream>>>(feats2, w2t, b2, ss2, partials, y3mx, y3mn);
  reduce_kernel<<<64, 256, 0, stream>>>(partials, stats3, 256);
  finalize_kernel<<<1, 128, 0, stream>>>(stats3, g2, be2, ss3, 128);
  bn3_out_kernel<<<512, 256, 0, stream>>>(y3mx, y3mn, ss3, out);
}